// Round 1
// baseline (390.453 us; speedup 1.0000x reference)
//
#include <hip/hip_runtime.h>
#include <hip/hip_bf16.h>

#define TOKENS 16384
#define HIDDEN 4096
#define EXPERTS 64

typedef __attribute__((ext_vector_type(8))) short short8;
typedef __attribute__((ext_vector_type(4))) float f32x4;

// Dequantized weights in MFMA B-fragment order:
// index = ((kk*4 + nt)*64 + lane)*8 + j
//   expert e = nt*16 + (lane&15),  k = kk*32 + (lane>>4)*8 + j
// 128 kk-steps * 4 n-tiles * 64 lanes * 8 elems = 262144 ushorts = 512 KB
__device__ ushort g_B[128 * 4 * 64 * 8];

union Frag {
    uint4 u;
    short8 s;
};

__device__ __forceinline__ ushort f2bf_rtne(float f) {
    union { float f; unsigned u; } c; c.f = f;
    unsigned u = c.u;
    // round-to-nearest-even; inputs are finite normals (no NaN handling needed)
    return (ushort)((u + 0x7FFF + ((u >> 16) & 1)) >> 16);
}

__device__ __forceinline__ unsigned pk_bf16(float lo, float hi) {
    __hip_bfloat162 h = __float22bfloat162_rn(make_float2(lo, hi));
    unsigned r;
    __builtin_memcpy(&r, &h, 4);
    return r;
}

// One thread per g_B element (262144 threads): also zeroes d_out (4 floats each)
// since the split-K main kernel accumulates with atomics into it.
__global__ __launch_bounds__(256) void prep_kernel(const int* __restrict__ w,
                                                   const float* __restrict__ sc,
                                                   float* __restrict__ out) {
    int tid = blockIdx.x * 256 + threadIdx.x;   // 0..262143
    reinterpret_cast<float4*>(out)[tid] = make_float4(0.f, 0.f, 0.f, 0.f);

    int j    = tid & 7;
    int lane = (tid >> 3) & 63;
    int nt   = (tid >> 9) & 3;
    int kk   = tid >> 11;
    int e = nt * 16 + (lane & 15);
    int k = kk * 32 + (lane >> 4) * 8 + j;
    float v = (float)w[e * HIDDEN + k] * sc[e];
    g_B[tid] = f2bf_rtne(v);
}

// Grid: (256 M-blocks, 4 K-quarters). Block: 256 threads = 4 waves.
// Wave: 16 tokens x 64 experts, K range = 1024 (32 MFMA K-steps of 32).
__global__ __launch_bounds__(256, 4) void moe_router_kernel(const float* __restrict__ x,
                                                            float* __restrict__ out) {
    const int mb   = blockIdx.x;          // 0..255
    const int kq   = blockIdx.y;          // 0..3
    const int wave = threadIdx.x >> 6;    // 0..3
    const int lane = threadIdx.x & 63;

    const int row0 = mb * 64 + wave * 16;
    const int m    = row0 + (lane & 15);
    const int kb   = kq * 1024 + (lane >> 4) * 8;

    const float*  xp = x + (size_t)m * HIDDEN + kb;
    const ushort* bp = g_B + (size_t)kq * 65536 + lane * 8;  // kk = kq*32, nt = 0

    f32x4 acc0 = {0.f, 0.f, 0.f, 0.f};
    f32x4 acc1 = {0.f, 0.f, 0.f, 0.f};
    f32x4 acc2 = {0.f, 0.f, 0.f, 0.f};
    f32x4 acc3 = {0.f, 0.f, 0.f, 0.f};

#pragma unroll 4
    for (int s = 0; s < 32; ++s) {
        // A fragment: 8 consecutive fp32 of this token's row (two float4 loads;
        // 4 lanes with same row cover one contiguous 128B line — coalesced)
        float4 a0 = *reinterpret_cast<const float4*>(xp + s * 32);
        float4 a1 = *reinterpret_cast<const float4*>(xp + s * 32 + 4);
        Frag af;
        af.u.x = pk_bf16(a0.x, a0.y);
        af.u.y = pk_bf16(a0.z, a0.w);
        af.u.z = pk_bf16(a1.x, a1.y);
        af.u.w = pk_bf16(a1.z, a1.w);

        // B fragments: 16B per lane, 1KB contiguous per wave-load (L2-hot)
        const uint4* bq = reinterpret_cast<const uint4*>(bp + (size_t)s * 2048);
        Frag b0, b1, b2, b3;
        b0.u = bq[0];    // nt=0 (+0    ushorts)
        b1.u = bq[64];   // nt=1 (+512  ushorts)
        b2.u = bq[128];  // nt=2 (+1024 ushorts)
        b3.u = bq[192];  // nt=3 (+1536 ushorts)

        acc0 = __builtin_amdgcn_mfma_f32_16x16x32_bf16(af.s, b0.s, acc0, 0, 0, 0);
        acc1 = __builtin_amdgcn_mfma_f32_16x16x32_bf16(af.s, b1.s, acc1, 0, 0, 0);
        acc2 = __builtin_amdgcn_mfma_f32_16x16x32_bf16(af.s, b2.s, acc2, 0, 0, 0);
        acc3 = __builtin_amdgcn_mfma_f32_16x16x32_bf16(af.s, b3.s, acc3, 0, 0, 0);
    }

    // Epilogue: C/D layout col = lane&15, row = (lane>>4)*4 + r  [m89/m91-verified]
    const int trow = row0 + (lane >> 4) * 4;
    const int col  = lane & 15;
    float* op = out + (size_t)trow * EXPERTS + col;
#pragma unroll
    for (int r = 0; r < 4; ++r) {
        atomicAdd(op + (size_t)r * EXPERTS + 0,  acc0[r]);
        atomicAdd(op + (size_t)r * EXPERTS + 16, acc1[r]);
        atomicAdd(op + (size_t)r * EXPERTS + 32, acc2[r]);
        atomicAdd(op + (size_t)r * EXPERTS + 48, acc3[r]);
    }
}

extern "C" void kernel_launch(void* const* d_in, const int* in_sizes, int n_in,
                              void* d_out, int out_size, void* d_ws, size_t ws_size,
                              hipStream_t stream) {
    const float* x  = (const float*)d_in[0];
    const int*   w  = (const int*)d_in[1];
    const float* sc = (const float*)d_in[2];
    float* out = (float*)d_out;

    // prep: dequant weights into fragment layout + zero the output accumulator
    prep_kernel<<<1024, 256, 0, stream>>>(w, sc, out);

    // main: split-K=4 MFMA GEMM, atomic fp32 accumulation
    dim3 grid(TOKENS / 64, 4);
    moe_router_kernel<<<grid, 256, 0, stream>>>(x, out);
}

// Round 2
// 383.656 us; speedup vs baseline: 1.0177x; 1.0177x over previous
//
#include <hip/hip_runtime.h>
#include <hip/hip_bf16.h>

#define TOKENS 16384
#define HIDDEN 4096
#define EXPERTS 64

typedef __attribute__((ext_vector_type(8))) short short8;
typedef __attribute__((ext_vector_type(4))) float f32x4;

// Dequantized weights in MFMA B-fragment order:
// index = ((kk*4 + nt)*64 + lane)*8 + j
//   expert e = nt*16 + (lane&15),  k = kk*32 + (lane>>4)*8 + j
// 128 kk-steps * 4 n-tiles * 64 lanes * 8 elems = 262144 ushorts = 512 KB
__device__ ushort g_B[128 * 4 * 64 * 8];

union Frag {
    uint4 u;
    short8 s;
};

__device__ __forceinline__ ushort f2bf_rtne(float f) {
    union { float f; unsigned u; } c; c.f = f;
    unsigned u = c.u;
    return (ushort)((u + 0x7FFF + ((u >> 16) & 1)) >> 16);
}

__device__ __forceinline__ unsigned pk_bf16(float lo, float hi) {
    __hip_bfloat162 h = __float22bfloat162_rn(make_float2(lo, hi));
    unsigned r;
    __builtin_memcpy(&r, &h, 4);
    return r;
}

// One thread per g_B element (262144 threads). No d_out zeroing needed anymore
// (epilogue is a plain store, not atomic accumulation).
__global__ __launch_bounds__(256) void prep_kernel(const int* __restrict__ w,
                                                   const float* __restrict__ sc) {
    int tid = blockIdx.x * 256 + threadIdx.x;   // 0..262143
    int j    = tid & 7;
    int lane = (tid >> 3) & 63;
    int nt   = (tid >> 9) & 3;
    int kk   = tid >> 11;
    int e = nt * 16 + (lane & 15);
    int k = kk * 32 + (lane >> 4) * 8 + j;
    float v = (float)w[e * HIDDEN + k] * sc[e];
    g_B[tid] = f2bf_rtne(v);
}

// Grid: 256 blocks (one per CU), 1024 threads = 16 waves = 4 row-groups x 4 K-quarters.
// Wave (rg, kq): 16 tokens x 64 experts over K-quarter kq (32 MFMA K-steps of 32).
// Cross-kq reduction in LDS, single coalesced float4 store epilogue — no atomics.
__global__ __launch_bounds__(1024, 4) void moe_router_kernel(const float* __restrict__ x,
                                                             float* __restrict__ out) {
    // stride 68 floats = 272 B: breaks power-of-2 banking (2-way max = free),
    // stays 16B-aligned for float4 access in the reduction phase.
    __shared__ __align__(16) float lds[4][64][68];

    const int mb   = blockIdx.x;          // 0..255
    const int wave = threadIdx.x >> 6;    // 0..15
    const int lane = threadIdx.x & 63;
    const int rg   = wave & 3;            // row-group within the 64-row block tile
    const int kq   = wave >> 2;           // K-quarter

    const int rowl = rg * 16 + (lane & 15);
    const int m    = mb * 64 + rowl;
    const int kb   = kq * 1024 + (lane >> 4) * 8;

    const float*  xp = x + (size_t)m * HIDDEN + kb;
    const ushort* bp = g_B + (size_t)kq * 65536 + lane * 8;  // kk = kq*32, nt = 0

    f32x4 acc0 = {0.f, 0.f, 0.f, 0.f};
    f32x4 acc1 = {0.f, 0.f, 0.f, 0.f};
    f32x4 acc2 = {0.f, 0.f, 0.f, 0.f};
    f32x4 acc3 = {0.f, 0.f, 0.f, 0.f};

#pragma unroll 4
    for (int s = 0; s < 32; ++s) {
        // A fragment: 8 consecutive fp32 of this token's row; the 4 lanes sharing
        // a row cover one contiguous 128B segment — fully coalesced.
        float4 a0 = *reinterpret_cast<const float4*>(xp + s * 32);
        float4 a1 = *reinterpret_cast<const float4*>(xp + s * 32 + 4);
        Frag af;
        af.u.x = pk_bf16(a0.x, a0.y);
        af.u.y = pk_bf16(a0.z, a0.w);
        af.u.z = pk_bf16(a1.x, a1.y);
        af.u.w = pk_bf16(a1.z, a1.w);

        // B fragments: 16B/lane, 1KB contiguous per wave-load (L2-resident table)
        const uint4* bq = reinterpret_cast<const uint4*>(bp + (size_t)s * 2048);
        Frag b0, b1, b2, b3;
        b0.u = bq[0];    // experts  0..15
        b1.u = bq[64];   // experts 16..31
        b2.u = bq[128];  // experts 32..47
        b3.u = bq[192];  // experts 48..63

        acc0 = __builtin_amdgcn_mfma_f32_16x16x32_bf16(af.s, b0.s, acc0, 0, 0, 0);
        acc1 = __builtin_amdgcn_mfma_f32_16x16x32_bf16(af.s, b1.s, acc1, 0, 0, 0);
        acc2 = __builtin_amdgcn_mfma_f32_16x16x32_bf16(af.s, b2.s, acc2, 0, 0, 0);
        acc3 = __builtin_amdgcn_mfma_f32_16x16x32_bf16(af.s, b3.s, acc3, 0, 0, 0);
    }

    // Partial write: C/D layout col = lane&15, row = (lane>>4)*4 + r  [m89/m91]
    // Per ds_write: 4 rows x 16 cols -> 2-way bank aliasing only (free).
    const int lrow = rg * 16 + (lane >> 4) * 4;
    const int col  = lane & 15;
#pragma unroll
    for (int r = 0; r < 4; ++r) {
        lds[kq][lrow + r][col +  0] = acc0[r];
        lds[kq][lrow + r][col + 16] = acc1[r];
        lds[kq][lrow + r][col + 32] = acc2[r];
        lds[kq][lrow + r][col + 48] = acc3[r];
    }
    __syncthreads();

    // Reduce 4 K-quarters and store: thread t -> row t>>4, cols (t&15)*4 .. +3.
    // Each wave stores 4 full rows = 1KB contiguous — perfectly coalesced dwordx4.
    const int t    = threadIdx.x;
    const int rrow = t >> 4;
    const int rcol = (t & 15) * 4;
    float4 s0 = *reinterpret_cast<const float4*>(&lds[0][rrow][rcol]);
    float4 s1 = *reinterpret_cast<const float4*>(&lds[1][rrow][rcol]);
    float4 s2 = *reinterpret_cast<const float4*>(&lds[2][rrow][rcol]);
    float4 s3 = *reinterpret_cast<const float4*>(&lds[3][rrow][rcol]);
    float4 r4;
    r4.x = (s0.x + s1.x) + (s2.x + s3.x);
    r4.y = (s0.y + s1.y) + (s2.y + s3.y);
    r4.z = (s0.z + s1.z) + (s2.z + s3.z);
    r4.w = (s0.w + s1.w) + (s2.w + s3.w);
    *reinterpret_cast<float4*>(out + ((size_t)mb * 64 + rrow) * EXPERTS + rcol) = r4;
}

extern "C" void kernel_launch(void* const* d_in, const int* in_sizes, int n_in,
                              void* d_out, int out_size, void* d_ws, size_t ws_size,
                              hipStream_t stream) {
    const float* x  = (const float*)d_in[0];
    const int*   w  = (const int*)d_in[1];
    const float* sc = (const float*)d_in[2];
    float* out = (float*)d_out;

    // prep: dequant weights into MFMA fragment layout (512 KB, L2-resident)
    prep_kernel<<<1024, 256, 0, stream>>>(w, sc);

    // main: one block per CU, LDS cross-K reduction, no atomics
    moe_router_kernel<<<TOKENS / 64, 1024, 0, stream>>>(x, out);
}

// Round 4
// 373.047 us; speedup vs baseline: 1.0467x; 1.0284x over previous
//
#include <hip/hip_runtime.h>
#include <hip/hip_bf16.h>

#define TOKENS 16384
#define HIDDEN 4096
#define EXPERTS 64

typedef __attribute__((ext_vector_type(8))) short short8;
typedef __attribute__((ext_vector_type(4))) float f32x4;
typedef __attribute__((ext_vector_type(4))) unsigned int u32x4;

// Dequantized weights in MFMA B-fragment order:
// index = ((kk*4 + nt)*64 + lane)*8 + j
//   expert e = nt*16 + (lane&15),  k = kk*32 + (lane>>4)*8 + j
// 128 kk * 4 nt * 64 lanes * 8 = 262144 ushorts = 512 KB (L2-resident)
__device__ ushort g_B[128 * 4 * 64 * 8];

union Frag {
    u32x4 u;
    short8 s;
};

__device__ __forceinline__ ushort f2bf_rtne(float f) {
    union { float f; unsigned u; } c; c.f = f;
    unsigned u = c.u;
    return (ushort)((u + 0x7FFF + ((u >> 16) & 1)) >> 16);
}

__device__ __forceinline__ unsigned pk_bf16(float lo, float hi) {
    __hip_bfloat162 h = __float22bfloat162_rn(make_float2(lo, hi));
    unsigned r;
    __builtin_memcpy(&r, &h, 4);
    return r;
}

__global__ __launch_bounds__(256) void prep_kernel(const int* __restrict__ w,
                                                   const float* __restrict__ sc) {
    int tid = blockIdx.x * 256 + threadIdx.x;   // 0..262143
    int j    = tid & 7;
    int lane = (tid >> 3) & 63;
    int nt   = (tid >> 9) & 3;
    int kk   = tid >> 11;
    int e = nt * 16 + (lane & 15);
    int k = kk * 32 + (lane >> 4) * 8 + j;
    float v = (float)w[e * HIDDEN + k] * sc[e];
    g_B[tid] = f2bf_rtne(v);
}

// Grid: 256 blocks, 1024 threads = 16 waves = 4 row-groups x 4 K-quarters.
// Depth-1 software pipeline: A (HBM, nontemporal) and B (L2) for iter s+1 are
// issued before the MFMAs of iter s, so MFMA waitcnts only cover loads that
// are already ~1 full iteration old. Live VGPRs ~95 < 128 cap: no spills.
__global__ __launch_bounds__(1024, 4) void moe_router_kernel(const float* __restrict__ x,
                                                             float* __restrict__ out) {
    // stride 68 floats = 272 B: breaks power-of-2 banking, 16B-aligned.
    __shared__ __align__(16) float lds[4][64][68];

    const int mb   = blockIdx.x;          // 0..255
    const int wave = threadIdx.x >> 6;    // 0..15
    const int lane = threadIdx.x & 63;
    const int rg   = wave & 3;            // row-group
    const int kq   = wave >> 2;           // K-quarter

    const int rowl = rg * 16 + (lane & 15);
    const int m    = mb * 64 + rowl;
    const int kb   = kq * 1024 + (lane >> 4) * 8;

    const float*  xs = x + (size_t)m * HIDDEN + kb;
    const ushort* bs = g_B + (size_t)kq * 65536 + lane * 8;  // kk = kq*32, nt = 0

    f32x4 acc0 = {0.f, 0.f, 0.f, 0.f};
    f32x4 acc1 = {0.f, 0.f, 0.f, 0.f};
    f32x4 acc2 = {0.f, 0.f, 0.f, 0.f};
    f32x4 acc3 = {0.f, 0.f, 0.f, 0.f};

    // ---- pipeline prologue: iter-0 loads ----
    f32x4 a0n = __builtin_nontemporal_load(reinterpret_cast<const f32x4*>(xs));
    f32x4 a1n = __builtin_nontemporal_load(reinterpret_cast<const f32x4*>(xs) + 1);
    const u32x4* bq = reinterpret_cast<const u32x4*>(bs);
    u32x4 b0n = bq[0], b1n = bq[64], b2n = bq[128], b3n = bq[192];
    xs += 32;
    bs += 2048;

    for (int s = 0; s < 32; ++s) {
        f32x4 a0 = a0n, a1 = a1n;
        Frag b0, b1, b2, b3;
        b0.u = b0n; b1.u = b1n; b2.u = b2n; b3.u = b3n;

        if (s < 31) {
            // issue next iteration's loads BEFORE consuming current
            a0n = __builtin_nontemporal_load(reinterpret_cast<const f32x4*>(xs));
            a1n = __builtin_nontemporal_load(reinterpret_cast<const f32x4*>(xs) + 1);
            const u32x4* bq2 = reinterpret_cast<const u32x4*>(bs);
            b0n = bq2[0]; b1n = bq2[64]; b2n = bq2[128]; b3n = bq2[192];
            xs += 32;
            bs += 2048;
        }

        Frag af;
        af.u.x = pk_bf16(a0.x, a0.y);
        af.u.y = pk_bf16(a0.z, a0.w);
        af.u.z = pk_bf16(a1.x, a1.y);
        af.u.w = pk_bf16(a1.z, a1.w);

        acc0 = __builtin_amdgcn_mfma_f32_16x16x32_bf16(af.s, b0.s, acc0, 0, 0, 0);
        acc1 = __builtin_amdgcn_mfma_f32_16x16x32_bf16(af.s, b1.s, acc1, 0, 0, 0);
        acc2 = __builtin_amdgcn_mfma_f32_16x16x32_bf16(af.s, b2.s, acc2, 0, 0, 0);
        acc3 = __builtin_amdgcn_mfma_f32_16x16x32_bf16(af.s, b3.s, acc3, 0, 0, 0);
    }

    // Partial write to LDS: C/D layout col = lane&15, row = (lane>>4)*4 + r
    const int lrow = rg * 16 + (lane >> 4) * 4;
    const int col  = lane & 15;
#pragma unroll
    for (int r = 0; r < 4; ++r) {
        lds[kq][lrow + r][col +  0] = acc0[r];
        lds[kq][lrow + r][col + 16] = acc1[r];
        lds[kq][lrow + r][col + 32] = acc2[r];
        lds[kq][lrow + r][col + 48] = acc3[r];
    }
    __syncthreads();

    // Reduce 4 K-quarters, coalesced float4 store (1 KB/wave contiguous).
    const int t    = threadIdx.x;
    const int rrow = t >> 4;
    const int rcol = (t & 15) * 4;
    float4 s0 = *reinterpret_cast<const float4*>(&lds[0][rrow][rcol]);
    float4 s1 = *reinterpret_cast<const float4*>(&lds[1][rrow][rcol]);
    float4 s2 = *reinterpret_cast<const float4*>(&lds[2][rrow][rcol]);
    float4 s3 = *reinterpret_cast<const float4*>(&lds[3][rrow][rcol]);
    float4 r4;
    r4.x = (s0.x + s1.x) + (s2.x + s3.x);
    r4.y = (s0.y + s1.y) + (s2.y + s3.y);
    r4.z = (s0.z + s1.z) + (s2.z + s3.z);
    r4.w = (s0.w + s1.w) + (s2.w + s3.w);
    *reinterpret_cast<float4*>(out + ((size_t)mb * 64 + rrow) * EXPERTS + rcol) = r4;
}

extern "C" void kernel_launch(void* const* d_in, const int* in_sizes, int n_in,
                              void* d_out, int out_size, void* d_ws, size_t ws_size,
                              hipStream_t stream) {
    const float* x  = (const float*)d_in[0];
    const int*   w  = (const int*)d_in[1];
    const float* sc = (const float*)d_in[2];
    float* out = (float*)d_out;

    prep_kernel<<<1024, 256, 0, stream>>>(w, sc);
    moe_router_kernel<<<TOKENS / 64, 1024, 0, stream>>>(x, out);
}

// Round 5
// 352.643 us; speedup vs baseline: 1.1072x; 1.0579x over previous
//
#include <hip/hip_runtime.h>
#include <hip/hip_bf16.h>

#define TOKENS 16384
#define HIDDEN 4096
#define EXPERTS 64

typedef __attribute__((ext_vector_type(8))) short short8;
typedef __attribute__((ext_vector_type(4))) float f32x4;
typedef __attribute__((ext_vector_type(4))) unsigned int u32x4;

// Dequantized weights in MFMA B-fragment order (uint4 granularity):
//   uint4 index = kk*256 + nt*64 + lane   (kk = K-chunk of 32, nt = expert group)
//   lane's 8 ushorts j=0..7: expert e = nt*16+(lane&15), k = kk*32+(lane>>4)*8+j
// 128 kk * 4 nt * 64 lanes = 32768 uint4 = 512 KB (L2/L3-resident)
__device__ __align__(16) ushort g_B[128 * 4 * 64 * 8];

union Frag {
    u32x4 u;
    short8 s;
};

__device__ __forceinline__ ushort f2bf_rtne(float f) {
    union { float f; unsigned u; } c; c.f = f;
    unsigned u = c.u;
    return (ushort)((u + 0x7FFF + ((u >> 16) & 1)) >> 16);
}

__device__ __forceinline__ unsigned pk_bf16(float lo, float hi) {
    __hip_bfloat162 h = __float22bfloat162_rn(make_float2(lo, hi));
    unsigned r;
    __builtin_memcpy(&r, &h, 4);
    return r;
}

__device__ __forceinline__ void loadA(const float* p, f32x4& a0, f32x4& a1) {
    a0 = __builtin_nontemporal_load(reinterpret_cast<const f32x4*>(p));
    a1 = __builtin_nontemporal_load(reinterpret_cast<const f32x4*>(p) + 1);
}

// One thread per g_B element (262144 threads); also zeroes d_out (4 floats each,
// 262144*4 = 1M floats) for the split-K atomic accumulation in the main kernel.
__global__ __launch_bounds__(256) void prep_kernel(const int* __restrict__ w,
                                                   const float* __restrict__ sc,
                                                   float* __restrict__ out) {
    int tid = blockIdx.x * 256 + threadIdx.x;   // 0..262143
    reinterpret_cast<float4*>(out)[tid] = make_float4(0.f, 0.f, 0.f, 0.f);

    int j    = tid & 7;
    int lane = (tid >> 3) & 63;
    int nt   = (tid >> 9) & 3;
    int kk   = tid >> 11;
    int e = nt * 16 + (lane & 15);
    int k = kk * 32 + (lane >> 4) * 8 + j;
    float v = (float)w[e * HIDDEN + k] * sc[e];
    g_B[tid] = f2bf_rtne(v);
}

// Grid: (128 row-blocks, 8 K-slices). Block: 512 threads = 8 waves x 16 rows.
// B-slice (64 experts x 512 k = 64 KB) staged once into LDS; K-loop VMEM is
// ONLY the A stream (2 nontemporal dwordx4/iter, depth-2 register prefetch).
// B frags via ds_read_b128 (lgkm pipe). 2 blocks/CU resident (LDS 2x64 KB,
// VGPR <= 128). Cross-kq partials accumulate via fp32 atomicAdd (out zeroed
// in prep).
__global__ __launch_bounds__(512, 4) void moe_router_kernel(const float* __restrict__ x,
                                                            float* __restrict__ out) {
    __shared__ u32x4 smB[4096];   // exactly 64 KB

    const int mb   = blockIdx.x;          // 0..127
    const int kq   = blockIdx.y;          // 0..7
    const int tid  = threadIdx.x;
    const int wave = tid >> 6;            // 0..7
    const int lane = tid & 63;

    // ---- stage B slice: 4096 uint4, 8 per thread, linear copy ----
    const u32x4* gB = reinterpret_cast<const u32x4*>(g_B) + (size_t)kq * 4096;
#pragma unroll
    for (int i = 0; i < 8; ++i) smB[tid + i * 512] = gB[tid + i * 512];
    __syncthreads();

    const int row0 = mb * 128 + wave * 16;
    const int m    = row0 + (lane & 15);
    const int kb   = kq * 512 + (lane >> 4) * 8;
    const float* xs = x + (size_t)m * HIDDEN + kb;

    f32x4 acc0 = {0.f, 0.f, 0.f, 0.f};
    f32x4 acc1 = {0.f, 0.f, 0.f, 0.f};
    f32x4 acc2 = {0.f, 0.f, 0.f, 0.f};
    f32x4 acc3 = {0.f, 0.f, 0.f, 0.f};

    // ---- prologue: A for s=0,1 in flight; B frags for s=0 ----
    f32x4 a0c, a1c, a0n, a1n;
    loadA(xs, a0c, a1c);
    loadA(xs + 32, a0n, a1n);
    u32x4 b0c = smB[lane];
    u32x4 b1c = smB[lane + 64];
    u32x4 b2c = smB[lane + 128];
    u32x4 b3c = smB[lane + 192];

    for (int s = 0; s < 16; ++s) {
        // prefetch A(s+2) — keeps 2 iterations (4 KB/wave) of HBM loads in flight
        f32x4 a0f = a0n, a1f = a1n;
        if (s < 14) loadA(xs + (s + 2) * 32, a0f, a1f);

        // prefetch B(s+1) frags from LDS
        u32x4 b0n = b0c, b1n = b1c, b2n = b2c, b3n = b3c;
        if (s < 15) {
            const u32x4* bp = smB + (s + 1) * 256 + lane;
            b0n = bp[0];
            b1n = bp[64];
            b2n = bp[128];
            b3n = bp[192];
        }

        // pack current A into bf16 fragment
        Frag af;
        af.u.x = pk_bf16(a0c.x, a0c.y);
        af.u.y = pk_bf16(a0c.z, a0c.w);
        af.u.z = pk_bf16(a1c.x, a1c.y);
        af.u.w = pk_bf16(a1c.z, a1c.w);

        Frag b0, b1, b2, b3;
        b0.u = b0c; b1.u = b1c; b2.u = b2c; b3.u = b3c;
        acc0 = __builtin_amdgcn_mfma_f32_16x16x32_bf16(af.s, b0.s, acc0, 0, 0, 0);
        acc1 = __builtin_amdgcn_mfma_f32_16x16x32_bf16(af.s, b1.s, acc1, 0, 0, 0);
        acc2 = __builtin_amdgcn_mfma_f32_16x16x32_bf16(af.s, b2.s, acc2, 0, 0, 0);
        acc3 = __builtin_amdgcn_mfma_f32_16x16x32_bf16(af.s, b3.s, acc3, 0, 0, 0);

        // rotate pipeline registers
        a0c = a0n; a1c = a1n; a0n = a0f; a1n = a1f;
        b0c = b0n; b1c = b1n; b2c = b2n; b3c = b3n;
    }

    // Epilogue: C/D layout col = lane&15, row = (lane>>4)*4 + r  [m89/m91]
    // 16 lanes -> 64B contiguous spans; 8.4M atomics total (~free per R1/R2 A/B)
    const int trow = row0 + (lane >> 4) * 4;
    const int col  = lane & 15;
    float* op = out + (size_t)trow * EXPERTS + col;
#pragma unroll
    for (int r = 0; r < 4; ++r) {
        atomicAdd(op + (size_t)r * EXPERTS + 0,  acc0[r]);
        atomicAdd(op + (size_t)r * EXPERTS + 16, acc1[r]);
        atomicAdd(op + (size_t)r * EXPERTS + 32, acc2[r]);
        atomicAdd(op + (size_t)r * EXPERTS + 48, acc3[r]);
    }
}

extern "C" void kernel_launch(void* const* d_in, const int* in_sizes, int n_in,
                              void* d_out, int out_size, void* d_ws, size_t ws_size,
                              hipStream_t stream) {
    const float* x  = (const float*)d_in[0];
    const int*   w  = (const int*)d_in[1];
    const float* sc = (const float*)d_in[2];
    float* out = (float*)d_out;

    // prep: dequant weights into MFMA fragment layout + zero output accumulator
    prep_kernel<<<1024, 256, 0, stream>>>(w, sc, out);

    // main: B-in-LDS, pure A-stream VMEM, split-K=8 with atomic accumulation
    dim3 grid(TOKENS / 128, 8);
    moe_router_kernel<<<grid, 512, 0, stream>>>(x, out);
}